// Round 16
// baseline (2932.605 us; speedup 1.0000x reference)
//
#include <hip/hip_runtime.h>
#include <math.h>

#define TT      1024
#define BATCH   512
#define UNITSN  256
#define ZDIM    1024
#define NFEAT   32
#define OSTEPS  32
#define NBND    31
#define OUT_MU  (BATCH*OSTEPS*NFEAT)   // 524288
#define OUT_SG  (OUT_MU + BATCH)

#define NQR     23     // i8 weight slots in VGPRs (92 regs; ~112 total <= 128 budget)
#define NQL     9      // i8 weight slots in LDS (9*8KB = 72 KiB)
#define HQS     36     // dwords per (buf,khalf-region) h block (32 + 4 pad)
#define HQ(buf,reg) (((buf)*2+(reg))*HQS)

__device__ __forceinline__ float sigm(float x)  { return 1.0f / (1.0f + __expf(-x)); }
__device__ __forceinline__ float ftanh(float x) { float e = __expf(2.0f * x); return 1.0f - 2.0f / (e + 1.0f); }

__device__ __forceinline__ int dot4i8(unsigned int a, unsigned int b, int c) {
#if __has_builtin(__builtin_amdgcn_sdot4)
    return __builtin_amdgcn_sdot4((int)a, (int)b, c, false);
#else
    int r = c;
    #pragma unroll
    for (int i = 0; i < 4; ++i) {
        r += (int)(signed char)(a >> (8*i)) * (int)(signed char)(b >> (8*i));
    }
    return r;
#endif
}

// ---------------- _T_BASE on device (fp64, mirrors the numpy code) -------------
__global__ void k_tbase(float* __restrict__ tb) {
    int i = threadIdx.x;
    if (i >= NBND) return;
    double step = (0.9999 - 0.0001) / 30.0;
    double p = 0.0001 + (double)i * step;
    if (i == 30) p = 0.9999;

    const double a0=-39.69683028665376, a1=220.9460984245205, a2=-275.9285104469687,
                 a3=138.357751867269,   a4=-30.66479806614716, a5=2.506628277459239;
    const double b0=-54.47609879822406, b1=161.5858368580409, b2=-155.6989798598866,
                 b3=66.80131188771972,  b4=-13.28068155288572;
    const double c0=-0.007784894002430293, c1=-0.3223964580411365, c2=-2.400758277161838,
                 c3=-2.549732539343734,    c4=4.374664141464968,   c5=2.938163982698783;
    const double d0=0.007784695709041462,  d1=0.3224671290700398,  d2=2.445134137142996,
                 d3=3.754408661907416;
    const double lo = 0.02425, hi = 1.0 - 0.02425;
    double z;
    if (p < lo) {
        double q = sqrt(-2.0 * log(p));
        z = (((((c0*q+c1)*q+c2)*q+c3)*q+c4)*q+c5) / ((((d0*q+d1)*q+d2)*q+d3)*q+1.0);
    } else if (p <= hi) {
        double q = p - 0.5;
        double r = q*q;
        z = (((((a0*r+a1)*r+a2)*r+a3)*r+a4)*r+a5)*q /
            (((((b0*r+b1)*r+b2)*r+b3)*r+b4)*r+1.0);
    } else {
        double q = sqrt(-2.0 * log(1.0 - p));
        z = -((((((c0*q+c1)*q+c2)*q+c3)*q+c4)*q+c5) / ((((d0*q+d1)*q+d2)*q+d3)*q+1.0));
    }
    double z2=z*z, z3=z2*z, z5=z3*z2, z7=z5*z2, z9=z7*z2;
    double g1=(z3+z)/4.0;
    double g2=(5.0*z5+16.0*z3+3.0*z)/96.0;
    double g3=(3.0*z7+19.0*z5+17.0*z3-15.0*z)/384.0;
    double g4=(79.0*z9+776.0*z7+1482.0*z5-1920.0*z3-945.0*z)/92160.0;
    const double df = 15.0;
    double t = z + g1/df + g2/(df*df) + g3/(df*df*df) + g4/(df*df*df*df);
    tb[i] = (float)t;
}

// ---------------- per-row mean / std ----------------
__global__ __launch_bounds__(1024)
void k_musig(const float* __restrict__ x, float* __restrict__ out,
             float* __restrict__ muv, float* __restrict__ sgv) {
    int b = blockIdx.x;
    int t = threadIdx.x;
    __shared__ float red[16];
    __shared__ float sMu;
    float v = x[(size_t)b * TT + t];

    float s = v;
    #pragma unroll
    for (int o = 32; o >= 1; o >>= 1) { s += __shfl_xor(s, o, 64); }
    int wid = t >> 6, lane = t & 63;
    if (lane == 0) red[wid] = s;
    __syncthreads();
    if (t == 0) {
        float tot = 0.f;
        for (int w = 0; w < 16; ++w) tot += red[w];
        sMu = tot * (1.0f / 1024.0f);
    }
    __syncthreads();
    float mu = sMu;
    float d = v - mu;
    s = d * d;
    #pragma unroll
    for (int o = 32; o >= 1; o >>= 1) { s += __shfl_xor(s, o, 64); }
    if (lane == 0) red[wid] = s;
    __syncthreads();
    if (t == 0) {
        float tot = 0.f;
        for (int w = 0; w < 16; ++w) tot += red[w];
        float sg = sqrtf(tot * (1.0f / 1024.0f));
        out[OUT_MU + b] = mu;
        out[OUT_SG + b] = sg;
        muv[b] = mu;
        sgv[b] = sg;
    }
}

// ---------------- per-gate-column scales ----------------
__global__ __launch_bounds__(256)
void k_scales(const float* __restrict__ Rec, float* __restrict__ SW,
              float* __restrict__ SInv) {
    int j = blockIdx.x * 256 + threadIdx.x;   // < 1024
    float m = 0.f;
    for (int k = 0; k < 256; ++k) m = fmaxf(m, fabsf(Rec[(size_t)k * ZDIM + j]));
    SW[j]   = m * (1.0f / 16129.0f);
    SInv[j] = (m > 0.f) ? (127.0f / m) : 0.f;
}

// ---------------- i8 weight pack: [slot][tid] uint4 (4 gate-dwords of 4 k each) ---
// consumer thread t=(u=t>>1, kh=t&1); slot s covers global k = kh*128 + 4s .. +3.
__global__ __launch_bounds__(256)
void k_packQ(const float* __restrict__ Rec, const float* __restrict__ SInv,
             uint4* __restrict__ Q) {
    int e = blockIdx.x * 256 + threadIdx.x;   // < 16384
    int s = e >> 9, t = e & 511;
    int u = t >> 1, kh = t & 1;
    int k0 = kh * 128 + s * 4;
    unsigned int d[4];
    #pragma unroll
    for (int g = 0; g < 4; ++g) {
        int j = g * 256 + u;
        float inv = SInv[j];
        unsigned int dw = 0;
        #pragma unroll
        for (int i = 0; i < 4; ++i) {
            int q = __float2int_rn(Rec[(size_t)(k0 + i) * ZDIM + j] * inv);
            dw |= ((unsigned int)(q & 0xff)) << (8 * i);
        }
        d[g] = dw;
    }
    Q[e] = make_uint4(d[0], d[1], d[2], d[3]);
}

// KB[i*1024 + u*4 + g] = Kmat[i][g*256+u] + Bias[g*256+u]   (bias folded: rows sum to 1)
__global__ __launch_bounds__(256)
void k_packK(const float* __restrict__ Kmat, const float* __restrict__ Bias,
             float* __restrict__ KB) {
    int e = blockIdx.x * 256 + threadIdx.x;   // 0..32767
    int i = e >> 10, c = e & 1023;
    int u = c >> 2, g = c & 3;
    int j = g * 256 + u;
    KB[e] = Kmat[(size_t)i * ZDIM + j] + Bias[j];
}

// ---------------- fully-resident int8 LSTM: 512 blocks x 512 thr, 1 row/block -----
// thread = (u = tid>>1, kh = tid&1). 32 i8 k-quad slots/thread: 23 VGPR + 9 LDS
// (72KB slab; total LDS ~77KB -> 2 blocks/CU, 4 waves/SIMD). Per-thread 128 dot4.
// Paired lanes combine via one shfl_xor; both compute gates redundantly (no branch).
__global__ __launch_bounds__(512)
void k_lstm16(const float* __restrict__ x,
              const uint4* __restrict__ Q,       // [32 slots][512 tid] i8 weights
              const float* __restrict__ SW,      // [1024] combined scales
              const float* __restrict__ KB,      // [32][256][4] kernel+bias fp32
              const float* __restrict__ Dw,      // (256,32)
              const float* __restrict__ Db,      // (32)
              const float* __restrict__ tb,
              const float* __restrict__ muv,
              const float* __restrict__ sgv,
              float* __restrict__ out)
{
    __shared__ uint4 sWq[NQL * 512];            // 72 KiB resident i8 weight slab
    __shared__ unsigned int sHq[2 * 2 * HQS];   // i8 h, dbuf x 2 khalf-regions
    __shared__ float sHT[UNITSN];               // fp32 h for dense head
    __shared__ unsigned char sIdx[TT];
    __shared__ float sBnd[32];
    __shared__ float sPT[NFEAT];
    __shared__ float sLog[NFEAT];

    const int tid = threadIdx.x;
    const int u   = tid >> 1;
    const int kh  = tid & 1;
    const int row = blockIdx.x;                 // one batch row per block

    // ---- one-time staging ----
    if (tid < 32) {
        if (tid < NBND) sBnd[tid] = tb[tid] * sgv[row] + muv[row];
    }
    if (tid < 2 * 2 * HQS) sHq[tid] = 0u;
    if (tid < UNITSN) sHT[tid] = 0.f;

    uint4 Wreg[NQR];
    #pragma unroll
    for (int j = 0; j < NQR; ++j) {
        uint4 w = Q[j * 512 + tid];
        asm volatile("" : "+v"(w.x), "+v"(w.y), "+v"(w.z), "+v"(w.w));
        Wreg[j] = w;
    }
    #pragma unroll
    for (int l = 0; l < NQL; ++l) {
        sWq[l * 512 + tid] = Q[(NQR + l) * 512 + tid];
    }

    // per-thread gate scales
    float4 SW4 = make_float4(SW[u], SW[256 + u], SW[512 + u], SW[768 + u]);

    for (int t = tid; t < TT; t += 512) {
        float xv = x[(size_t)row * TT + t];
        int id = 0;
        #pragma unroll
        for (int q = 0; q < NBND; ++q) { id += (sBnd[q] <= xv) ? 1 : 0; }
        sIdx[t] = (unsigned char)id;
    }
    __syncthreads();

    float cC = 0.f;
    int cur = 0;
    const int wbyte_reg = u >> 7;      // which khalf-region this unit's h lands in
    const int wbyte_off = u & 127;

    auto stepCore = [&](float4 kbSelf) {
        const unsigned int* hb = &sHq[HQ(cur, kh)];
        int4 A = {0, 0, 0, 0};
        #pragma unroll
        for (int s4 = 0; s4 < 8; ++s4) {
            uint4 hh = *(const uint4*)(hb + s4 * 4);
            #pragma unroll
            for (int i = 0; i < 4; ++i) {
                const int j = s4 * 4 + i;
                uint4 w = (j < NQR) ? Wreg[(j < NQR) ? j : 0]
                                    : sWq[(j - NQR) * 512 + tid];
                unsigned int h0 = (i==0)?hh.x:(i==1)?hh.y:(i==2)?hh.z:hh.w;
                A.x = dot4i8(h0, w.x, A.x); A.y = dot4i8(h0, w.y, A.y);
                A.z = dot4i8(h0, w.z, A.z); A.w = dot4i8(h0, w.w, A.w);
            }
        }
        // combine k-halves with adjacent lane (tid^1); both lanes get the full sum
        A.x += __shfl_xor(A.x, 1); A.y += __shfl_xor(A.y, 1);
        A.z += __shfl_xor(A.z, 1); A.w += __shfl_xor(A.w, 1);
        float zi = (float)A.x * SW4.x + kbSelf.x;
        float zf = (float)A.y * SW4.y + kbSelf.y;
        float zg = (float)A.z * SW4.z + kbSelf.z;
        float zo = (float)A.w * SW4.w + kbSelf.w;
        cC = sigm(zf) * cC + sigm(zi) * ftanh(zg);
        float hv = sigm(zo) * ftanh(cC);
        if (kh == 0) {
            sHT[u] = hv;
            int qh = __float2int_rn(hv * 127.0f);   // |hv| < 1 strictly
            ((unsigned char*)sHq)[(HQ(cur ^ 1, wbyte_reg) << 2) + wbyte_off] =
                (unsigned char)qh;
        }
        cur ^= 1;
        __syncthreads();
    };

    auto softmaxStore = [&](int s) {
        if (tid < NFEAT) {
            int f = tid;
            float acc = Db[f];
            #pragma unroll 4
            for (int uu = 0; uu < UNITSN; ++uu) {
                acc = fmaf(sHT[uu], Dw[uu * NFEAT + f], acc);
            }
            sLog[f] = acc;
        }
        __syncthreads();
        if (tid == 0) {
            float mx = sLog[0];
            for (int f = 1; f < NFEAT; ++f) mx = fmaxf(mx, sLog[f]);
            float ssum = 0.f;
            for (int f = 0; f < NFEAT; ++f) {
                float e = __expf(sLog[f] - mx);
                sLog[f] = e;
                ssum += e;
            }
            float inv = 1.0f / ssum;
            for (int f = 0; f < NFEAT; ++f) {
                float p = sLog[f] * inv;
                sPT[f] = p;
                out[((size_t)row * OSTEPS + s) * NFEAT + f] = p;
            }
        }
        __syncthreads();
    };

    // ---------------- encoder: 1024 steps ----------------
    #pragma unroll 1
    for (int t = 0; t < TT; ++t) {
        float4 kb = *(const float4*)&KB[((int)sIdx[t] << 10) + (u << 2)];
        stepCore(kb);
    }
    softmaxStore(0);

    // ---------------- decoder: 31 steps ----------------
    #pragma unroll 1
    for (int s = 1; s < OSTEPS; ++s) {
        float4 a = make_float4(0.f, 0.f, 0.f, 0.f);
        #pragma unroll
        for (int ii = 0; ii < 16; ++ii) {
            int i = kh * 16 + ii;
            float4 w = *(const float4*)&KB[(i << 10) + (u << 2)];
            float p = sPT[i];
            a.x = fmaf(p, w.x, a.x); a.y = fmaf(p, w.y, a.y);
            a.z = fmaf(p, w.z, a.z); a.w = fmaf(p, w.w, a.w);
        }
        // combine input-side partials across k-halves; both lanes get the sum
        a.x += __shfl_xor(a.x, 1); a.y += __shfl_xor(a.y, 1);
        a.z += __shfl_xor(a.z, 1); a.w += __shfl_xor(a.w, 1);
        stepCore(a);
        softmaxStore(s);
    }
}

extern "C" void kernel_launch(void* const* d_in, const int* in_sizes, int n_in,
                              void* d_out, int out_size, void* d_ws, size_t ws_size,
                              hipStream_t stream) {
    const float* inputs = (const float*)d_in[0];
    const float* kernel = (const float*)d_in[1];
    const float* rec    = (const float*)d_in[2];
    const float* bias   = (const float*)d_in[3];
    const float* dw     = (const float*)d_in[4];
    const float* db     = (const float*)d_in[5];
    float* out = (float*)d_out;

    // ws layout: tb 64f | muv 512f | sgv 512f -> 4352B | SW 4KB | SInv 4KB |
    //            Q 256KB | KB 128KB  => 405760B total (< proven ws_size 659712)
    float* tbp  = (float*)d_ws;
    float* muv  = tbp + 64;
    float* sgv  = muv + BATCH;
    float* SW   = (float*)((char*)d_ws + 4352);
    float* SInv = (float*)((char*)d_ws + 8448);
    uint4* Q    = (uint4*)((char*)d_ws + 12544);
    float* KB   = (float*)((char*)d_ws + 12544 + 262144);

    k_tbase<<<1, 32, 0, stream>>>(tbp);
    k_musig<<<BATCH, 1024, 0, stream>>>(inputs, out, muv, sgv);
    k_scales<<<4, 256, 0, stream>>>(rec, SW, SInv);
    k_packQ<<<64, 256, 0, stream>>>(rec, SInv, Q);
    k_packK<<<128, 256, 0, stream>>>(kernel, bias, KB);
    k_lstm16<<<BATCH, 512, 0, stream>>>(inputs, Q, SW, KB, dw, db,
                                        tbp, muv, sgv, out);
}

// Round 17
// 2896.322 us; speedup vs baseline: 1.0125x; 1.0125x over previous
//
#include <hip/hip_runtime.h>
#include <math.h>

#define TT      1024
#define BATCH   512
#define UNITSN  256
#define ZDIM    1024
#define NFEAT   32
#define OSTEPS  32
#define NBND    31
#define OUT_MU  (BATCH*OSTEPS*NFEAT)   // 524288
#define OUT_SG  (OUT_MU + BATCH)

#define NQR     25     // i8 weight slots in VGPRs (100 regs; ~126 total <= 128 budget)
#define NQL     7      // i8 weight slots in LDS (7*8KB = 56 KiB -> block LDS < 64KB)
#define HQS     36     // dwords per (buf,khalf-region) h block (32 + 4 pad)
#define HQ(buf,reg) (((buf)*2+(reg))*HQS)

__device__ __forceinline__ float sigm(float x)  { return 1.0f / (1.0f + __expf(-x)); }
__device__ __forceinline__ float ftanh(float x) { float e = __expf(2.0f * x); return 1.0f - 2.0f / (e + 1.0f); }

__device__ __forceinline__ int dot4i8(unsigned int a, unsigned int b, int c) {
#if __has_builtin(__builtin_amdgcn_sdot4)
    return __builtin_amdgcn_sdot4((int)a, (int)b, c, false);
#else
    int r = c;
    #pragma unroll
    for (int i = 0; i < 4; ++i) {
        r += (int)(signed char)(a >> (8*i)) * (int)(signed char)(b >> (8*i));
    }
    return r;
#endif
}

// ---------------- _T_BASE on device (fp64, mirrors the numpy code) -------------
__global__ void k_tbase(float* __restrict__ tb) {
    int i = threadIdx.x;
    if (i >= NBND) return;
    double step = (0.9999 - 0.0001) / 30.0;
    double p = 0.0001 + (double)i * step;
    if (i == 30) p = 0.9999;

    const double a0=-39.69683028665376, a1=220.9460984245205, a2=-275.9285104469687,
                 a3=138.357751867269,   a4=-30.66479806614716, a5=2.506628277459239;
    const double b0=-54.47609879822406, b1=161.5858368580409, b2=-155.6989798598866,
                 b3=66.80131188771972,  b4=-13.28068155288572;
    const double c0=-0.007784894002430293, c1=-0.3223964580411365, c2=-2.400758277161838,
                 c3=-2.549732539343734,    c4=4.374664141464968,   c5=2.938163982698783;
    const double d0=0.007784695709041462,  d1=0.3224671290700398,  d2=2.445134137142996,
                 d3=3.754408661907416;
    const double lo = 0.02425, hi = 1.0 - 0.02425;
    double z;
    if (p < lo) {
        double q = sqrt(-2.0 * log(p));
        z = (((((c0*q+c1)*q+c2)*q+c3)*q+c4)*q+c5) / ((((d0*q+d1)*q+d2)*q+d3)*q+1.0);
    } else if (p <= hi) {
        double q = p - 0.5;
        double r = q*q;
        z = (((((a0*r+a1)*r+a2)*r+a3)*r+a4)*r+a5)*q /
            (((((b0*r+b1)*r+b2)*r+b3)*r+b4)*r+1.0);
    } else {
        double q = sqrt(-2.0 * log(1.0 - p));
        z = -((((((c0*q+c1)*q+c2)*q+c3)*q+c4)*q+c5) / ((((d0*q+d1)*q+d2)*q+d3)*q+1.0));
    }
    double z2=z*z, z3=z2*z, z5=z3*z2, z7=z5*z2, z9=z7*z2;
    double g1=(z3+z)/4.0;
    double g2=(5.0*z5+16.0*z3+3.0*z)/96.0;
    double g3=(3.0*z7+19.0*z5+17.0*z3-15.0*z)/384.0;
    double g4=(79.0*z9+776.0*z7+1482.0*z5-1920.0*z3-945.0*z)/92160.0;
    const double df = 15.0;
    double t = z + g1/df + g2/(df*df) + g3/(df*df*df) + g4/(df*df*df*df);
    tb[i] = (float)t;
}

// ---------------- per-row mean / std ----------------
__global__ __launch_bounds__(1024)
void k_musig(const float* __restrict__ x, float* __restrict__ out,
             float* __restrict__ muv, float* __restrict__ sgv) {
    int b = blockIdx.x;
    int t = threadIdx.x;
    __shared__ float red[16];
    __shared__ float sMu;
    float v = x[(size_t)b * TT + t];

    float s = v;
    #pragma unroll
    for (int o = 32; o >= 1; o >>= 1) { s += __shfl_xor(s, o, 64); }
    int wid = t >> 6, lane = t & 63;
    if (lane == 0) red[wid] = s;
    __syncthreads();
    if (t == 0) {
        float tot = 0.f;
        for (int w = 0; w < 16; ++w) tot += red[w];
        sMu = tot * (1.0f / 1024.0f);
    }
    __syncthreads();
    float mu = sMu;
    float d = v - mu;
    s = d * d;
    #pragma unroll
    for (int o = 32; o >= 1; o >>= 1) { s += __shfl_xor(s, o, 64); }
    if (lane == 0) red[wid] = s;
    __syncthreads();
    if (t == 0) {
        float tot = 0.f;
        for (int w = 0; w < 16; ++w) tot += red[w];
        float sg = sqrtf(tot * (1.0f / 1024.0f));
        out[OUT_MU + b] = mu;
        out[OUT_SG + b] = sg;
        muv[b] = mu;
        sgv[b] = sg;
    }
}

// ---------------- per-gate-column scales ----------------
__global__ __launch_bounds__(256)
void k_scales(const float* __restrict__ Rec, float* __restrict__ SW,
              float* __restrict__ SInv) {
    int j = blockIdx.x * 256 + threadIdx.x;   // < 1024
    float m = 0.f;
    for (int k = 0; k < 256; ++k) m = fmaxf(m, fabsf(Rec[(size_t)k * ZDIM + j]));
    SW[j]   = m * (1.0f / 16129.0f);
    SInv[j] = (m > 0.f) ? (127.0f / m) : 0.f;
}

// ---------------- i8 weight pack: [slot][tid] uint4 (4 gate-dwords of 4 k each) ---
// consumer thread t=(u=t>>1, kh=t&1); slot s covers global k = kh*128 + 4s .. +3.
__global__ __launch_bounds__(256)
void k_packQ(const float* __restrict__ Rec, const float* __restrict__ SInv,
             uint4* __restrict__ Q) {
    int e = blockIdx.x * 256 + threadIdx.x;   // < 16384
    int s = e >> 9, t = e & 511;
    int u = t >> 1, kh = t & 1;
    int k0 = kh * 128 + s * 4;
    unsigned int d[4];
    #pragma unroll
    for (int g = 0; g < 4; ++g) {
        int j = g * 256 + u;
        float inv = SInv[j];
        unsigned int dw = 0;
        #pragma unroll
        for (int i = 0; i < 4; ++i) {
            int q = __float2int_rn(Rec[(size_t)(k0 + i) * ZDIM + j] * inv);
            dw |= ((unsigned int)(q & 0xff)) << (8 * i);
        }
        d[g] = dw;
    }
    Q[e] = make_uint4(d[0], d[1], d[2], d[3]);
}

// KB[i*1024 + u*4 + g] = Kmat[i][g*256+u] + Bias[g*256+u]   (bias folded: rows sum to 1)
__global__ __launch_bounds__(256)
void k_packK(const float* __restrict__ Kmat, const float* __restrict__ Bias,
             float* __restrict__ KB) {
    int e = blockIdx.x * 256 + threadIdx.x;   // 0..32767
    int i = e >> 10, c = e & 1023;
    int u = c >> 2, g = c & 3;
    int j = g * 256 + u;
    KB[e] = Kmat[(size_t)i * ZDIM + j] + Bias[j];
}

// ---------------- fully-resident int8 LSTM: 512 blocks x 512 thr, 1 row/block -----
// thread = (u = tid>>1, kh = tid&1). 32 i8 k-quad slots/thread: 25 VGPR + 7 LDS
// (56KB slab; total LDS ~59KB < 64KB -> 2 blocks/CU, 4 waves/SIMD). 128 dot4/thread.
// Paired lanes combine via one shfl_xor; both compute gates redundantly (no branch).
__global__ __launch_bounds__(512)
void k_lstm17(const float* __restrict__ x,
              const uint4* __restrict__ Q,       // [32 slots][512 tid] i8 weights
              const float* __restrict__ SW,      // [1024] combined scales
              const float* __restrict__ KB,      // [32][256][4] kernel+bias fp32
              const float* __restrict__ Dw,      // (256,32)
              const float* __restrict__ Db,      // (32)
              const float* __restrict__ tb,
              const float* __restrict__ muv,
              const float* __restrict__ sgv,
              float* __restrict__ out)
{
    __shared__ uint4 sWq[NQL * 512];            // 56 KiB resident i8 weight slab
    __shared__ unsigned int sHq[2 * 2 * HQS];   // i8 h, dbuf x 2 khalf-regions
    __shared__ float sHT[UNITSN];               // fp32 h for dense head
    __shared__ unsigned char sIdx[TT];
    __shared__ float sBnd[32];
    __shared__ float sPT[NFEAT];
    __shared__ float sLog[NFEAT];

    const int tid = threadIdx.x;
    const int u   = tid >> 1;
    const int kh  = tid & 1;
    const int row = blockIdx.x;                 // one batch row per block

    // ---- one-time staging ----
    if (tid < 32) {
        if (tid < NBND) sBnd[tid] = tb[tid] * sgv[row] + muv[row];
    }
    if (tid < 2 * 2 * HQS) sHq[tid] = 0u;
    if (tid < UNITSN) sHT[tid] = 0.f;

    uint4 Wreg[NQR];
    #pragma unroll
    for (int j = 0; j < NQR; ++j) {
        uint4 w = Q[j * 512 + tid];
        asm volatile("" : "+v"(w.x), "+v"(w.y), "+v"(w.z), "+v"(w.w));
        Wreg[j] = w;
    }
    #pragma unroll
    for (int l = 0; l < NQL; ++l) {
        sWq[l * 512 + tid] = Q[(NQR + l) * 512 + tid];
    }

    // per-thread gate scales
    float4 SW4 = make_float4(SW[u], SW[256 + u], SW[512 + u], SW[768 + u]);

    for (int t = tid; t < TT; t += 512) {
        float xv = x[(size_t)row * TT + t];
        int id = 0;
        #pragma unroll
        for (int q = 0; q < NBND; ++q) { id += (sBnd[q] <= xv) ? 1 : 0; }
        sIdx[t] = (unsigned char)id;
    }
    __syncthreads();

    float cC = 0.f;
    int cur = 0;
    const int wbyte_reg = u >> 7;      // which khalf-region this unit's h lands in
    const int wbyte_off = u & 127;

    auto stepCore = [&](float4 kbSelf) {
        const unsigned int* hb = &sHq[HQ(cur, kh)];
        int4 A = {0, 0, 0, 0};
        #pragma unroll
        for (int s4 = 0; s4 < 8; ++s4) {
            uint4 hh = *(const uint4*)(hb + s4 * 4);
            #pragma unroll
            for (int i = 0; i < 4; ++i) {
                const int j = s4 * 4 + i;
                uint4 w = (j < NQR) ? Wreg[(j < NQR) ? j : 0]
                                    : sWq[(j - NQR) * 512 + tid];
                unsigned int h0 = (i==0)?hh.x:(i==1)?hh.y:(i==2)?hh.z:hh.w;
                A.x = dot4i8(h0, w.x, A.x); A.y = dot4i8(h0, w.y, A.y);
                A.z = dot4i8(h0, w.z, A.z); A.w = dot4i8(h0, w.w, A.w);
            }
        }
        // combine k-halves with adjacent lane (tid^1); both lanes get the full sum
        A.x += __shfl_xor(A.x, 1); A.y += __shfl_xor(A.y, 1);
        A.z += __shfl_xor(A.z, 1); A.w += __shfl_xor(A.w, 1);
        float zi = (float)A.x * SW4.x + kbSelf.x;
        float zf = (float)A.y * SW4.y + kbSelf.y;
        float zg = (float)A.z * SW4.z + kbSelf.z;
        float zo = (float)A.w * SW4.w + kbSelf.w;
        cC = sigm(zf) * cC + sigm(zi) * ftanh(zg);
        float hv = sigm(zo) * ftanh(cC);
        if (kh == 0) {
            sHT[u] = hv;
            int qh = __float2int_rn(hv * 127.0f);   // |hv| < 1 strictly
            ((unsigned char*)sHq)[(HQ(cur ^ 1, wbyte_reg) << 2) + wbyte_off] =
                (unsigned char)qh;
        }
        cur ^= 1;
        __syncthreads();
    };

    auto softmaxStore = [&](int s) {
        if (tid < NFEAT) {
            int f = tid;
            float acc = Db[f];
            #pragma unroll 4
            for (int uu = 0; uu < UNITSN; ++uu) {
                acc = fmaf(sHT[uu], Dw[uu * NFEAT + f], acc);
            }
            sLog[f] = acc;
        }
        __syncthreads();
        if (tid == 0) {
            float mx = sLog[0];
            for (int f = 1; f < NFEAT; ++f) mx = fmaxf(mx, sLog[f]);
            float ssum = 0.f;
            for (int f = 0; f < NFEAT; ++f) {
                float e = __expf(sLog[f] - mx);
                sLog[f] = e;
                ssum += e;
            }
            float inv = 1.0f / ssum;
            for (int f = 0; f < NFEAT; ++f) {
                float p = sLog[f] * inv;
                sPT[f] = p;
                out[((size_t)row * OSTEPS + s) * NFEAT + f] = p;
            }
        }
        __syncthreads();
    };

    // ---------------- encoder: 1024 steps ----------------
    #pragma unroll 1
    for (int t = 0; t < TT; ++t) {
        float4 kb = *(const float4*)&KB[((int)sIdx[t] << 10) + (u << 2)];
        stepCore(kb);
    }
    softmaxStore(0);

    // ---------------- decoder: 31 steps ----------------
    #pragma unroll 1
    for (int s = 1; s < OSTEPS; ++s) {
        float4 a = make_float4(0.f, 0.f, 0.f, 0.f);
        #pragma unroll
        for (int ii = 0; ii < 16; ++ii) {
            int i = kh * 16 + ii;
            float4 w = *(const float4*)&KB[(i << 10) + (u << 2)];
            float p = sPT[i];
            a.x = fmaf(p, w.x, a.x); a.y = fmaf(p, w.y, a.y);
            a.z = fmaf(p, w.z, a.z); a.w = fmaf(p, w.w, a.w);
        }
        // combine input-side partials across k-halves; both lanes get the sum
        a.x += __shfl_xor(a.x, 1); a.y += __shfl_xor(a.y, 1);
        a.z += __shfl_xor(a.z, 1); a.w += __shfl_xor(a.w, 1);
        stepCore(a);
        softmaxStore(s);
    }
}

extern "C" void kernel_launch(void* const* d_in, const int* in_sizes, int n_in,
                              void* d_out, int out_size, void* d_ws, size_t ws_size,
                              hipStream_t stream) {
    const float* inputs = (const float*)d_in[0];
    const float* kernel = (const float*)d_in[1];
    const float* rec    = (const float*)d_in[2];
    const float* bias   = (const float*)d_in[3];
    const float* dw     = (const float*)d_in[4];
    const float* db     = (const float*)d_in[5];
    float* out = (float*)d_out;

    // ws layout: tb 64f | muv 512f | sgv 512f -> 4352B | SW 4KB | SInv 4KB |
    //            Q 256KB | KB 128KB  => 405760B total (< proven ws_size 659712)
    float* tbp  = (float*)d_ws;
    float* muv  = tbp + 64;
    float* sgv  = muv + BATCH;
    float* SW   = (float*)((char*)d_ws + 4352);
    float* SInv = (float*)((char*)d_ws + 8448);
    uint4* Q    = (uint4*)((char*)d_ws + 12544);
    float* KB   = (float*)((char*)d_ws + 12544 + 262144);

    k_tbase<<<1, 32, 0, stream>>>(tbp);
    k_musig<<<BATCH, 1024, 0, stream>>>(inputs, out, muv, sgv);
    k_scales<<<4, 256, 0, stream>>>(rec, SW, SInv);
    k_packQ<<<64, 256, 0, stream>>>(rec, SInv, Q);
    k_packK<<<128, 256, 0, stream>>>(kernel, bias, KB);
    k_lstm17<<<BATCH, 512, 0, stream>>>(inputs, Q, SW, KB, dw, db,
                                        tbp, muv, sgv, out);
}

// Round 18
// 2038.952 us; speedup vs baseline: 1.4383x; 1.4205x over previous
//
#include <hip/hip_runtime.h>
#include <math.h>

#define TT      1024
#define BATCH   512
#define UNITSN  256
#define ZDIM    1024
#define NFEAT   32
#define OSTEPS  32
#define NBND    31
#define OUT_MU  (BATCH*OSTEPS*NFEAT)   // 524288
#define OUT_SG  (OUT_MU + BATCH)

#define NQR     22     // i8 weight slots in VGPRs (88 regs; 88+~32 working = 120 <= 128)
#define NQL     10     // i8 weight slots in LDS (10*8KB = 80 KiB)
#define HQS     36     // dwords per (buf,row,khalf-region) h block (32 + 4 pad)
#define HQ(buf,row,reg) ((((buf)*2+(row))*2+(reg))*HQS)

__device__ __forceinline__ float sigm(float x)  { return 1.0f / (1.0f + __expf(-x)); }
__device__ __forceinline__ float ftanh(float x) { float e = __expf(2.0f * x); return 1.0f - 2.0f / (e + 1.0f); }

__device__ __forceinline__ int dot4i8(unsigned int a, unsigned int b, int c) {
#if __has_builtin(__builtin_amdgcn_sdot4)
    return __builtin_amdgcn_sdot4((int)a, (int)b, c, false);
#else
    int r = c;
    #pragma unroll
    for (int i = 0; i < 4; ++i) {
        r += (int)(signed char)(a >> (8*i)) * (int)(signed char)(b >> (8*i));
    }
    return r;
#endif
}

// ---------------- _T_BASE on device (fp64, mirrors the numpy code) -------------
__global__ void k_tbase(float* __restrict__ tb) {
    int i = threadIdx.x;
    if (i >= NBND) return;
    double step = (0.9999 - 0.0001) / 30.0;
    double p = 0.0001 + (double)i * step;
    if (i == 30) p = 0.9999;

    const double a0=-39.69683028665376, a1=220.9460984245205, a2=-275.9285104469687,
                 a3=138.357751867269,   a4=-30.66479806614716, a5=2.506628277459239;
    const double b0=-54.47609879822406, b1=161.5858368580409, b2=-155.6989798598866,
                 b3=66.80131188771972,  b4=-13.28068155288572;
    const double c0=-0.007784894002430293, c1=-0.3223964580411365, c2=-2.400758277161838,
                 c3=-2.549732539343734,    c4=4.374664141464968,   c5=2.938163982698783;
    const double d0=0.007784695709041462,  d1=0.3224671290700398,  d2=2.445134137142996,
                 d3=3.754408661907416;
    const double lo = 0.02425, hi = 1.0 - 0.02425;
    double z;
    if (p < lo) {
        double q = sqrt(-2.0 * log(p));
        z = (((((c0*q+c1)*q+c2)*q+c3)*q+c4)*q+c5) / ((((d0*q+d1)*q+d2)*q+d3)*q+1.0);
    } else if (p <= hi) {
        double q = p - 0.5;
        double r = q*q;
        z = (((((a0*r+a1)*r+a2)*r+a3)*r+a4)*r+a5)*q /
            (((((b0*r+b1)*r+b2)*r+b3)*r+b4)*r+1.0);
    } else {
        double q = sqrt(-2.0 * log(1.0 - p));
        z = -((((((c0*q+c1)*q+c2)*q+c3)*q+c4)*q+c5) / ((((d0*q+d1)*q+d2)*q+d3)*q+1.0));
    }
    double z2=z*z, z3=z2*z, z5=z3*z2, z7=z5*z2, z9=z7*z2;
    double g1=(z3+z)/4.0;
    double g2=(5.0*z5+16.0*z3+3.0*z)/96.0;
    double g3=(3.0*z7+19.0*z5+17.0*z3-15.0*z)/384.0;
    double g4=(79.0*z9+776.0*z7+1482.0*z5-1920.0*z3-945.0*z)/92160.0;
    const double df = 15.0;
    double t = z + g1/df + g2/(df*df) + g3/(df*df*df) + g4/(df*df*df*df);
    tb[i] = (float)t;
}

// ---------------- per-row mean / std ----------------
__global__ __launch_bounds__(1024)
void k_musig(const float* __restrict__ x, float* __restrict__ out,
             float* __restrict__ muv, float* __restrict__ sgv) {
    int b = blockIdx.x;
    int t = threadIdx.x;
    __shared__ float red[16];
    __shared__ float sMu;
    float v = x[(size_t)b * TT + t];

    float s = v;
    #pragma unroll
    for (int o = 32; o >= 1; o >>= 1) { s += __shfl_xor(s, o, 64); }
    int wid = t >> 6, lane = t & 63;
    if (lane == 0) red[wid] = s;
    __syncthreads();
    if (t == 0) {
        float tot = 0.f;
        for (int w = 0; w < 16; ++w) tot += red[w];
        sMu = tot * (1.0f / 1024.0f);
    }
    __syncthreads();
    float mu = sMu;
    float d = v - mu;
    s = d * d;
    #pragma unroll
    for (int o = 32; o >= 1; o >>= 1) { s += __shfl_xor(s, o, 64); }
    if (lane == 0) red[wid] = s;
    __syncthreads();
    if (t == 0) {
        float tot = 0.f;
        for (int w = 0; w < 16; ++w) tot += red[w];
        float sg = sqrtf(tot * (1.0f / 1024.0f));
        out[OUT_MU + b] = mu;
        out[OUT_SG + b] = sg;
        muv[b] = mu;
        sgv[b] = sg;
    }
}

// ---------------- per-gate-column scales ----------------
__global__ __launch_bounds__(256)
void k_scales(const float* __restrict__ Rec, float* __restrict__ SW,
              float* __restrict__ SInv) {
    int j = blockIdx.x * 256 + threadIdx.x;   // < 1024
    float m = 0.f;
    for (int k = 0; k < 256; ++k) m = fmaxf(m, fabsf(Rec[(size_t)k * ZDIM + j]));
    SW[j]   = m * (1.0f / 16129.0f);
    SInv[j] = (m > 0.f) ? (127.0f / m) : 0.f;
}

// ---------------- i8 weight pack: [slot][tid] uint4 (4 gate-dwords of 4 k each) ---
// consumer thread t=(u=t>>1, kh=t&1); slot s covers global k = kh*128 + 4s .. +3.
__global__ __launch_bounds__(256)
void k_packQ(const float* __restrict__ Rec, const float* __restrict__ SInv,
             uint4* __restrict__ Q) {
    int e = blockIdx.x * 256 + threadIdx.x;   // < 16384
    int s = e >> 9, t = e & 511;
    int u = t >> 1, kh = t & 1;
    int k0 = kh * 128 + s * 4;
    unsigned int d[4];
    #pragma unroll
    for (int g = 0; g < 4; ++g) {
        int j = g * 256 + u;
        float inv = SInv[j];
        unsigned int dw = 0;
        #pragma unroll
        for (int i = 0; i < 4; ++i) {
            int q = __float2int_rn(Rec[(size_t)(k0 + i) * ZDIM + j] * inv);
            dw |= ((unsigned int)(q & 0xff)) << (8 * i);
        }
        d[g] = dw;
    }
    Q[e] = make_uint4(d[0], d[1], d[2], d[3]);
}

// KB[i*1024 + u*4 + g] = Kmat[i][g*256+u] + Bias[g*256+u]   (bias folded: rows sum to 1)
__global__ __launch_bounds__(256)
void k_packK(const float* __restrict__ Kmat, const float* __restrict__ Bias,
             float* __restrict__ KB) {
    int e = blockIdx.x * 256 + threadIdx.x;   // 0..32767
    int i = e >> 10, c = e & 1023;
    int u = c >> 2, g = c & 3;
    int j = g * 256 + u;
    KB[e] = Kmat[(size_t)i * ZDIM + j] + Bias[j];
}

// ---------------- fully-resident int8 LSTM: 256 blocks x 512 thr, 2 rows/block ----
// thread = (u = tid>>1, kh = tid&1). 32 i8 k-quad slots/thread: 22 VGPR + 10 LDS.
// Zero per-step global weight traffic; h kept as i8 in LDS (broadcast reads).
__global__ __launch_bounds__(512)
void k_lstm15(const float* __restrict__ x,
              const uint4* __restrict__ Q,       // [32 slots][512 tid] i8 weights
              const float* __restrict__ SW,      // [1024] combined scales
              const float* __restrict__ KB,      // [32][256][4] kernel+bias fp32
              const float* __restrict__ Dw,      // (256,32)
              const float* __restrict__ Db,      // (32)
              const float* __restrict__ tb,
              const float* __restrict__ muv,
              const float* __restrict__ sgv,
              float* __restrict__ out)
{
    __shared__ uint4 sWq[NQL * 512];            // 80 KiB resident i8 weight slab
    __shared__ unsigned int sHq[2 * 2 * 2 * HQS]; // i8 h, dbuf x 2 rows x 2 regions
    __shared__ float sHT[UNITSN][2];            // fp32 h for dense head
    __shared__ unsigned char sIdx[2][TT];
    __shared__ float sBnd[2][32];
    __shared__ float sPT[NFEAT][2];
    __shared__ float sLog[2][NFEAT];

    const int tid = threadIdx.x;
    const int u   = tid >> 1;
    const int kh  = tid & 1;
    const int b0  = blockIdx.x * 2;

    // ---- one-time staging ----
    if (tid < 64) {
        int rr = tid >> 5, j = tid & 31;
        if (j < NBND) sBnd[rr][j] = tb[j] * sgv[b0 + rr] + muv[b0 + rr];
    }
    if (tid < 2 * 2 * 2 * HQS) sHq[tid] = 0u;
    if (tid < UNITSN * 2) ((float*)sHT)[tid] = 0.f;

    uint4 Wreg[NQR];
    #pragma unroll
    for (int j = 0; j < NQR; ++j) {
        uint4 w = Q[j * 512 + tid];
        asm volatile("" : "+v"(w.x), "+v"(w.y), "+v"(w.z), "+v"(w.w));
        Wreg[j] = w;
    }
    #pragma unroll
    for (int l = 0; l < NQL; ++l) {
        sWq[l * 512 + tid] = Q[(NQR + l) * 512 + tid];
    }

    // per-thread gate scales
    float4 SW4 = make_float4(SW[u], SW[256 + u], SW[512 + u], SW[768 + u]);

    for (int e = tid; e < 2 * TT; e += 512) {
        int rr = e >> 10, t = e & 1023;
        float xv = x[(size_t)(b0 + rr) * TT + t];
        int id = 0;
        #pragma unroll
        for (int q = 0; q < NBND; ++q) { id += (sBnd[rr][q] <= xv) ? 1 : 0; }
        sIdx[rr][t] = (unsigned char)id;
    }
    __syncthreads();

    float cC = 0.f;
    int cur = 0;
    const int wbyte_reg = u >> 7;      // which khalf-region this unit's h lands in
    const int wbyte_off = u & 127;

    auto stepCore = [&](float4 kbSelf) {
        const unsigned int* hb0 = &sHq[HQ(cur, 0, kh)];
        const unsigned int* hb1 = &sHq[HQ(cur, 1, kh)];
        int4 A0 = {0, 0, 0, 0}, A1 = {0, 0, 0, 0};
        #pragma unroll
        for (int s4 = 0; s4 < 8; ++s4) {
            uint4 hh0 = *(const uint4*)(hb0 + s4 * 4);
            uint4 hh1 = *(const uint4*)(hb1 + s4 * 4);
            #pragma unroll
            for (int i = 0; i < 4; ++i) {
                const int j = s4 * 4 + i;
                uint4 w = (j < NQR) ? Wreg[(j < NQR) ? j : 0]
                                    : sWq[(j - NQR) * 512 + tid];
                unsigned int h0 = (i==0)?hh0.x:(i==1)?hh0.y:(i==2)?hh0.z:hh0.w;
                unsigned int h1 = (i==0)?hh1.x:(i==1)?hh1.y:(i==2)?hh1.z:hh1.w;
                A0.x = dot4i8(h0, w.x, A0.x); A0.y = dot4i8(h0, w.y, A0.y);
                A0.z = dot4i8(h0, w.z, A0.z); A0.w = dot4i8(h0, w.w, A0.w);
                A1.x = dot4i8(h1, w.x, A1.x); A1.y = dot4i8(h1, w.y, A1.y);
                A1.z = dot4i8(h1, w.z, A1.z); A1.w = dot4i8(h1, w.w, A1.w);
            }
        }
        // combine k-halves with adjacent lane (tid^1), int adds
        A0.x += __shfl_xor(A0.x, 1); A0.y += __shfl_xor(A0.y, 1);
        A0.z += __shfl_xor(A0.z, 1); A0.w += __shfl_xor(A0.w, 1);
        A1.x += __shfl_xor(A1.x, 1); A1.y += __shfl_xor(A1.y, 1);
        A1.z += __shfl_xor(A1.z, 1); A1.w += __shfl_xor(A1.w, 1);
        int qi = kh ? A1.x : A0.x;
        int qf = kh ? A1.y : A0.y;
        int qg = kh ? A1.z : A0.z;
        int qo = kh ? A1.w : A0.w;
        float zi = (float)qi * SW4.x + kbSelf.x;
        float zf = (float)qf * SW4.y + kbSelf.y;
        float zg = (float)qg * SW4.z + kbSelf.z;
        float zo = (float)qo * SW4.w + kbSelf.w;
        cC = sigm(zf) * cC + sigm(zi) * ftanh(zg);
        float hv = sigm(zo) * ftanh(cC);
        sHT[u][kh] = hv;
        int qh = __float2int_rn(hv * 127.0f);   // |hv| < 1 strictly -> no clamp needed
        ((unsigned char*)sHq)[(HQ(cur ^ 1, kh, wbyte_reg) << 2) + wbyte_off] =
            (unsigned char)qh;
        cur ^= 1;
        __syncthreads();
    };

    auto softmaxStore = [&](int s) {
        if (tid < 64) {
            int rr = tid >> 5, f = tid & 31;
            float acc = Db[f];
            #pragma unroll 4
            for (int uu = 0; uu < UNITSN; ++uu) {
                acc = fmaf(sHT[uu][rr], Dw[uu * NFEAT + f], acc);
            }
            sLog[rr][f] = acc;
        }
        __syncthreads();
        if (tid < 2) {
            int rr = tid;
            float mx = sLog[rr][0];
            for (int f = 1; f < NFEAT; ++f) mx = fmaxf(mx, sLog[rr][f]);
            float ssum = 0.f;
            for (int f = 0; f < NFEAT; ++f) {
                float e = __expf(sLog[rr][f] - mx);
                sLog[rr][f] = e;
                ssum += e;
            }
            float inv = 1.0f / ssum;
            for (int f = 0; f < NFEAT; ++f) {
                float p = sLog[rr][f] * inv;
                sPT[f][rr] = p;
                out[((size_t)(b0 + rr) * OSTEPS + s) * NFEAT + f] = p;
            }
        }
        __syncthreads();
    };

    // ---------------- encoder: 1024 steps ----------------
    #pragma unroll 1
    for (int t = 0; t < TT; ++t) {
        float4 kb = *(const float4*)&KB[((int)sIdx[kh][t] << 10) + (u << 2)];
        stepCore(kb);
    }
    softmaxStore(0);

    // ---------------- decoder: 31 steps ----------------
    #pragma unroll 1
    for (int s = 1; s < OSTEPS; ++s) {
        float4 a0 = make_float4(0.f, 0.f, 0.f, 0.f), a1 = a0;
        #pragma unroll
        for (int ii = 0; ii < 16; ++ii) {
            int i = kh * 16 + ii;
            float4 w = *(const float4*)&KB[(i << 10) + (u << 2)];
            float p0 = sPT[i][0], p1 = sPT[i][1];
            a0.x = fmaf(p0, w.x, a0.x); a0.y = fmaf(p0, w.y, a0.y);
            a0.z = fmaf(p0, w.z, a0.z); a0.w = fmaf(p0, w.w, a0.w);
            a1.x = fmaf(p1, w.x, a1.x); a1.y = fmaf(p1, w.y, a1.y);
            a1.z = fmaf(p1, w.z, a1.z); a1.w = fmaf(p1, w.w, a1.w);
        }
        // fp32 input-side combine across k-halves
        a0.x += __shfl_xor(a0.x, 1); a0.y += __shfl_xor(a0.y, 1);
        a0.z += __shfl_xor(a0.z, 1); a0.w += __shfl_xor(a0.w, 1);
        a1.x += __shfl_xor(a1.x, 1); a1.y += __shfl_xor(a1.y, 1);
        a1.z += __shfl_xor(a1.z, 1); a1.w += __shfl_xor(a1.w, 1);
        float4 kbSelf = (kh == 0) ? a0 : a1;
        stepCore(kbSelf);
        softmaxStore(s);
    }
}

extern "C" void kernel_launch(void* const* d_in, const int* in_sizes, int n_in,
                              void* d_out, int out_size, void* d_ws, size_t ws_size,
                              hipStream_t stream) {
    const float* inputs = (const float*)d_in[0];
    const float* kernel = (const float*)d_in[1];
    const float* rec    = (const float*)d_in[2];
    const float* bias   = (const float*)d_in[3];
    const float* dw     = (const float*)d_in[4];
    const float* db     = (const float*)d_in[5];
    float* out = (float*)d_out;

    // ws layout: tb 64f | muv 512f | sgv 512f -> 4352B | SW 4KB | SInv 4KB |
    //            Q 256KB | KB 128KB  => 405760B total (< proven ws_size 659712)
    float* tbp  = (float*)d_ws;
    float* muv  = tbp + 64;
    float* sgv  = muv + BATCH;
    float* SW   = (float*)((char*)d_ws + 4352);
    float* SInv = (float*)((char*)d_ws + 8448);
    uint4* Q    = (uint4*)((char*)d_ws + 12544);
    float* KB   = (float*)((char*)d_ws + 12544 + 262144);

    k_tbase<<<1, 32, 0, stream>>>(tbp);
    k_musig<<<BATCH, 1024, 0, stream>>>(inputs, out, muv, sgv);
    k_scales<<<4, 256, 0, stream>>>(rec, SW, SInv);
    k_packQ<<<64, 256, 0, stream>>>(rec, SInv, Q);
    k_packK<<<128, 256, 0, stream>>>(kernel, bias, KB);
    k_lstm15<<<BATCH / 2, 512, 0, stream>>>(inputs, Q, SW, KB, dw, db,
                                            tbp, muv, sgv, out);
}